// Round 11
// baseline (679.659 us; speedup 1.0000x reference)
//
#include <hip/hip_runtime.h>
#include <hip/hip_bf16.h>
#include <stdint.h>

#define BB 4
#define SS 4096
#define DD 256

typedef __attribute__((ext_vector_type(4))) float f32x4;
typedef __attribute__((ext_vector_type(8))) short s16x8;

__device__ __forceinline__ ushort f2bf(float f) {
  __hip_bfloat16 h = __float2bfloat16(f);
  return __builtin_bit_cast(ushort, h);
}

// ---------------- kernel 1: fp32 -> bf16 pack ----------------
__global__ void convert_kernel(const float* __restrict__ X,
                               const float* __restrict__ Wq,
                               const float* __restrict__ Wk,
                               const float* __restrict__ Wv,
                               const float* __restrict__ bq,
                               const float* __restrict__ bk,
                               const float* __restrict__ bv,
                               ushort* __restrict__ Xb,
                               ushort* __restrict__ Wb,
                               float* __restrict__ bias) {
  int tid = blockIdx.x * blockDim.x + threadIdx.x;
  int stride = gridDim.x * blockDim.x;
  const int NX4 = (BB * SS * DD) / 4;
  for (int i = tid; i < NX4; i += stride) {
    float4 v = ((const float4*)X)[i];
    ushort4 o = { f2bf(v.x), f2bf(v.y), f2bf(v.z), f2bf(v.w) };
    ((ushort4*)Xb)[i] = o;
  }
  const int NW4 = (DD * DD) / 4;
  for (int i = tid; i < NW4; i += stride) {
    float4 a = ((const float4*)Wq)[i];
    float4 b = ((const float4*)Wk)[i];
    float4 c = ((const float4*)Wv)[i];
    ushort4 oa = { f2bf(a.x), f2bf(a.y), f2bf(a.z), f2bf(a.w) };
    ushort4 ob = { f2bf(b.x), f2bf(b.y), f2bf(b.z), f2bf(b.w) };
    ushort4 oc = { f2bf(c.x), f2bf(c.y), f2bf(c.z), f2bf(c.w) };
    ((ushort4*)Wb)[i]           = oa;
    ((ushort4*)Wb)[NW4 + i]     = ob;
    ((ushort4*)Wb)[2 * NW4 + i] = oc;
  }
  if (tid < DD) {
    bias[tid]          = bq[tid];
    bias[DD + tid]     = bk[tid];
    bias[2 * DD + tid] = bv[tid];
  }
}

// ---------------- kernel 1b: mask bit-pack (runs AFTER proj_gemm) ----------------
// R8 counters: attn FETCH was 206 MB/dispatch, ~all the int32 mask (268 MB,
// 1 bit of info per 32 bits, zero reuse). Pack to 1 bit/element here
// (streaming-optimal); attn reads 8.4 MB instead. Pm ALIASES Xb's storage
// (both exactly 8,388,608 B): Xb is dead after proj_gemm, so total workspace
// stays at the R8-proven ~51 MB (R9's +8.4 MB grew it to 59 MB and the
// container died twice — suspected ws overflow -> OOB writes).
__global__ void maskpack_kernel(const int* __restrict__ mask,
                                unsigned long long* __restrict__ Pm) {
  const int tid = blockIdx.x * blockDim.x + threadIdx.x;
  const int wid = tid >> 6;
  const int lane = tid & 63;
  const int nw = (gridDim.x * blockDim.x) >> 6;
  const int NP = (BB * SS * SS) / 64;  // 1,048,576 words
  for (int i = wid; i < NP; i += nw) {
    const int v = mask[(size_t)i * 64 + lane];
    const unsigned long long bal = __ballot(v != 0);
    if (lane == 0) Pm[i] = bal;
  }
}

// ---------------- kernel 2: fused QKV projection GEMM ----------------
#define LROW 40  // padded LDS row stride (bf16 elems); 80B: multiple of 16B (b128-safe)

__global__ __launch_bounds__(256) void proj_gemm(const ushort* __restrict__ Xb,
                                                 const ushort* __restrict__ Wb,
                                                 const float* __restrict__ bias,
                                                 ushort* __restrict__ Qb,
                                                 ushort* __restrict__ Kb,
                                                 ushort* __restrict__ Vt) {
  __shared__ ushort Al[128 * LROW];
  __shared__ ushort Bl[128 * LROW];
  const int m0 = blockIdx.x * 128;
  const int n0 = blockIdx.y * 128;
  const int t = threadIdx.x;
  const int lane = t & 63;
  const int w = t >> 6;
  const int wr = w & 1, wc = w >> 1;
  const int col = lane & 15;
  const int quad = lane >> 4;

  f32x4 acc[4][4];
#pragma unroll
  for (int i = 0; i < 4; i++)
#pragma unroll
    for (int j = 0; j < 4; j++) acc[i][j] = f32x4{0.f, 0.f, 0.f, 0.f};

  const int ci0 = t, ci1 = 256 + t;
  const int r0 = ci0 >> 2, c0 = ci0 & 3;
  const int r1 = ci1 >> 2, c1 = ci1 & 3;

  s16x8 pa0 = *(const s16x8*)(Xb + (m0 + r0) * DD + c0 * 8);
  s16x8 pa1 = *(const s16x8*)(Xb + (m0 + r1) * DD + c1 * 8);
  s16x8 pb0 = *(const s16x8*)(Wb + (n0 + r0) * DD + c0 * 8);
  s16x8 pb1 = *(const s16x8*)(Wb + (n0 + r1) * DD + c1 * 8);

  for (int kk = 0; kk < DD; kk += 32) {
    __syncthreads();
    *(s16x8*)&Al[r0 * LROW + c0 * 8] = pa0;
    *(s16x8*)&Al[r1 * LROW + c1 * 8] = pa1;
    *(s16x8*)&Bl[r0 * LROW + c0 * 8] = pb0;
    *(s16x8*)&Bl[r1 * LROW + c1 * 8] = pb1;
    __syncthreads();
    const int kn = kk + 32;
    if (kn < DD) {
      pa0 = *(const s16x8*)(Xb + (m0 + r0) * DD + kn + c0 * 8);
      pa1 = *(const s16x8*)(Xb + (m0 + r1) * DD + kn + c1 * 8);
      pb0 = *(const s16x8*)(Wb + (n0 + r0) * DD + kn + c0 * 8);
      pb1 = *(const s16x8*)(Wb + (n0 + r1) * DD + kn + c1 * 8);
    }
    s16x8 af[4], bfr[4];
#pragma unroll
    for (int mi = 0; mi < 4; mi++)
      af[mi] = *(const s16x8*)&Al[(wr * 64 + mi * 16 + col) * LROW + quad * 8];
#pragma unroll
    for (int ni = 0; ni < 4; ni++)
      bfr[ni] = *(const s16x8*)&Bl[(wc * 64 + ni * 16 + col) * LROW + quad * 8];
#pragma unroll
    for (int mi = 0; mi < 4; mi++)
#pragma unroll
      for (int ni = 0; ni < 4; ni++)
        acc[mi][ni] = __builtin_amdgcn_mfma_f32_16x16x32_bf16(af[mi], bfr[ni], acc[mi][ni], 0, 0, 0);
  }

  const int region = n0 >> 8;  // 0=Q, 1=K, 2=V
#pragma unroll
  for (int mi = 0; mi < 4; mi++) {
    const int gm = m0 + wr * 64 + mi * 16 + quad * 4;
#pragma unroll
    for (int ni = 0; ni < 4; ni++) {
      const int gn = n0 + wc * 64 + ni * 16 + col;
      const float bb = bias[gn];
      f32x4 v = acc[mi][ni];
      if (region == 0) {
#pragma unroll
        for (int rg = 0; rg < 4; rg++)
          Qb[(gm + rg) * DD + gn] = f2bf((v[rg] + bb) * 0.015625f);  // exact /64
      } else if (region == 1) {
        const int d = gn - 256;
#pragma unroll
        for (int rg = 0; rg < 4; rg++)
          Kb[(gm + rg) * DD + d] = f2bf(v[rg] + bb);
      } else {
        const int d = gn - 512;
        const int b = gm >> 12;
        const int s = gm & (SS - 1);
        ushort4 o = { f2bf(v[0] + bb), f2bf(v[1] + bb), f2bf(v[2] + bb), f2bf(v[3] + bb) };
        *(ushort4*)&Vt[((size_t)(b << 8) + d) * SS + s] = o;
      }
    }
  }
}

// ---------------- kernel 3: flash attention ----------------
// Grid (64 qt, 4 b, 2 z): 512 blocks x 512 threads. Block z handles KV rows
// [z*2048, z*2048+2048) over 2 in-block KV groups; partials merged in LDS,
// then cross-z by merge_kernel. K/V time-share one LDS region (R8).
// Mask is bit-packed: 1 uint32/tile/q-row, broadcast across the 16 col lanes.
// OCCUPANCY NOTE (R7/R8): stuck at 8 waves/CU with LDS 42-75 KB and grid
// 2 blocks/CU — blocker is register file (108 arch VGPR + MFMA AGPRs > 128
// total), not LDS. ALIGNMENT RULE (R6): LDS row strides must be multiples of
// 8 ushorts (16 B) or ds_*_b128 splits into b64 pairs (3x per-tile cost).
#define NKT 32
#define KROW 264   // 528B, 16B-aligned
#define VROW 32    //  64B, 16B-aligned
#define PROW 32
#define MROW (SS / 32)  // 128 packed words per q row

#define KVREG_U 8448             // max(K tile 32*264=8448, V tile 256*32=8192)
#define PL_U (16 * PROW)         // 512 per wave
#define POFF (2 * KVREG_U)       // 16896
#define SM_U (POFF + 8 * PL_U)   // 20992 ushorts = 41984 B

// exchange slot: 72 f32 (m[4], l[4], O[64]); 2 waves/round: 128*72*4 = 36864 B
#define XSTRIDE 72

__global__ __launch_bounds__(512) void attn_kernel(const ushort* __restrict__ Qb,
                                                   const ushort* __restrict__ Kb,
                                                   const ushort* __restrict__ Vt,
                                                   const uint* __restrict__ Pm,
                                                   float* __restrict__ out,
                                                   float* __restrict__ O1,
                                                   float* __restrict__ Ml) {
  __shared__ __align__(16) ushort sm[SM_U];

  const int qt = blockIdx.x;  // 0..63
  const int b = blockIdx.y;   // 0..3
  const int z = blockIdx.z;   // 0..1 (KV half)
  const int t = threadIdx.x;
  const int g = t >> 8;       // in-block KV group: 0 or 1
  const int tg = t & 255;     // thread within group
  const int lane = t & 63;
  const int w = tg >> 6;      // row-wave within group: 0..3
  const int w8 = t >> 6;      // global wave: 0..7
  const int col = lane & 15;
  const int quad = lane >> 4;

  ushort* Kl = sm + g * KVREG_U;   // K and V time-share this region
  ushort* Vl = sm + g * KVREG_U;
  ushort* Pw = sm + POFF + w8 * PL_U;

  const int q0 = qt * 64;
  const int qrow = q0 + w * 16;  // wave's first q row (within batch)

  // Q fragments (A-operand), pre-scaled by 1/64
  s16x8 qf[8];
  {
    const ushort* qp = Qb + ((size_t)b * SS + qrow + col) * DD + quad * 8;
#pragma unroll
    for (int dc = 0; dc < 8; dc++) qf[dc] = *(const s16x8*)(qp + dc * 32);
  }

  int kr[4], kc[4], vd[4], vc[4];
#pragma unroll
  for (int i = 0; i < 4; i++) {
    const int ci = i * 256 + tg;
    kr[i] = ci >> 5; kc[i] = ci & 31;  // K tile: 32 rows x 32 chunks(8)
    vd[i] = ci >> 2; vc[i] = ci & 3;   // Vt tile: 256 d-rows x 4 chunks(8)
  }

  const ushort* Kg = Kb + (size_t)b * SS * DD;
  const ushort* Vg = Vt + (size_t)b * DD * SS;
  const uint* MgP = Pm + ((size_t)b * SS + qrow + quad * 4) * MROW;

  f32x4 Oc[16];
#pragma unroll
  for (int i = 0; i < 16; i++) Oc[i] = f32x4{0.f, 0.f, 0.f, 0.f};
  float m_i[4] = {-INFINITY, -INFINITY, -INFINITY, -INFINITY};
  float l_i[4] = {0.f, 0.f, 0.f, 0.f};

  const int NT2 = 1024 / NKT;             // 32 tiles per in-block group
  const int kb0 = z * 2048 + g * 1024;    // group's first kv position

  // prefetch this group's tile 0 into registers
  s16x8 pk[4], pv[4];
  uint pmw[4];
#pragma unroll
  for (int i = 0; i < 4; i++) {
    pk[i] = *(const s16x8*)(Kg + (size_t)(kb0 + kr[i]) * DD + kc[i] * 8);
    pv[i] = *(const s16x8*)(Vg + (size_t)vd[i] * SS + kb0 + vc[i] * 8);
  }
#pragma unroll
  for (int rg = 0; rg < 4; rg++) pmw[rg] = MgP[rg * MROW + (kb0 >> 5)];

  for (int tt = 0; tt < NT2; tt++) {
    __syncthreads();   // B1: prior PV reads of shared region done
#pragma unroll
    for (int i = 0; i < 4; i++)
      *(s16x8*)&Kl[kr[i] * KROW + kc[i] * 8] = pk[i];
    __syncthreads();   // B2: K tile visible
    uint mcur[4];
#pragma unroll
    for (int rg = 0; rg < 4; rg++) mcur[rg] = pmw[rg];
    const int k0n = kb0 + (tt + 1) * NKT;
    if (tt + 1 < NT2) {
#pragma unroll
      for (int i = 0; i < 4; i++)
        pk[i] = *(const s16x8*)(Kg + ((size_t)k0n + kr[i]) * DD + kc[i] * 8);
#pragma unroll
      for (int rg = 0; rg < 4; rg++) pmw[rg] = MgP[rg * MROW + (k0n >> 5)];
    }

    // S = Q K^T (pre-scaled): 2 col-tiles x 8 d-chunks
    f32x4 st[2];
    __builtin_amdgcn_s_setprio(1);
#pragma unroll
    for (int jt = 0; jt < 2; jt++) {
      f32x4 s = f32x4{0.f, 0.f, 0.f, 0.f};
#pragma unroll
      for (int dc = 0; dc < 8; dc++) {
        s16x8 kb = *(const s16x8*)&Kl[(jt * 16 + col) * KROW + dc * 32 + quad * 8];
        s = __builtin_amdgcn_mfma_f32_16x16x32_bf16(qf[dc], kb, s, 0, 0, 0);
      }
      st[jt] = s;
    }
    __builtin_amdgcn_s_setprio(0);
    // mask bit test (bit set -> -1e9, matching reference)
#pragma unroll
    for (int jt = 0; jt < 2; jt++)
#pragma unroll
      for (int rg = 0; rg < 4; rg++)
        if ((mcur[rg] >> (jt * 16 + col)) & 1u) st[jt][rg] = -1e9f;

    // online softmax: per q-row (row = quad*4+rg), reduce over 16 col lanes
    float al[4];
#pragma unroll
    for (int rg = 0; rg < 4; rg++) {
      float v = fmaxf(st[0][rg], st[1][rg]);
      v = fmaxf(v, __shfl_xor(v, 1));
      v = fmaxf(v, __shfl_xor(v, 2));
      v = fmaxf(v, __shfl_xor(v, 4));
      v = fmaxf(v, __shfl_xor(v, 8));
      const float mn = fmaxf(m_i[rg], v);
      al[rg] = __expf(m_i[rg] - mn);
      m_i[rg] = mn;
    }
#pragma unroll
    for (int rg = 0; rg < 4; rg++) {
      const float p0 = __expf(st[0][rg] - m_i[rg]);
      const float p1 = __expf(st[1][rg] - m_i[rg]);
      st[0][rg] = p0; st[1][rg] = p1;
      float s2 = p0 + p1;
      s2 += __shfl_xor(s2, 1);
      s2 += __shfl_xor(s2, 2);
      s2 += __shfl_xor(s2, 4);
      s2 += __shfl_xor(s2, 8);
      l_i[rg] = l_i[rg] * al[rg] + s2;
    }

    // P: C-layout -> LDS -> A-layout (own region, same-wave dependency only)
#pragma unroll
    for (int jt = 0; jt < 2; jt++)
#pragma unroll
      for (int rg = 0; rg < 4; rg++)
        Pw[(quad * 4 + rg) * PROW + jt * 16 + col] = f2bf(st[jt][rg]);
    s16x8 pa = *(const s16x8*)&Pw[col * PROW + quad * 8];

    // O rescale — EXACT skip: al==1.0 means multiply-by-1, identity.
    {
      const bool need = (al[0] < 1.f) | (al[1] < 1.f) | (al[2] < 1.f) | (al[3] < 1.f);
      if (__any(need)) {
#pragma unroll
        for (int dt = 0; dt < 16; dt++)
#pragma unroll
          for (int rg = 0; rg < 4; rg++) Oc[dt][rg] *= al[rg];
      }
    }

    __syncthreads();   // B3: all QK^T reads done; shared region free for V
#pragma unroll
    for (int i = 0; i < 4; i++)
      *(s16x8*)&Vl[vd[i] * VROW + vc[i] * 8] = pv[i];
    if (tt + 1 < NT2) {  // prefetch next V only after current V consumed
#pragma unroll
      for (int i = 0; i < 4; i++)
        pv[i] = *(const s16x8*)(Vg + (size_t)vd[i] * SS + k0n + vc[i] * 8);
    }
    __syncthreads();   // B4: V tile visible

    // O += P * V
    __builtin_amdgcn_s_setprio(1);
#pragma unroll
    for (int dt = 0; dt < 16; dt++) {
      s16x8 vb = *(const s16x8*)&Vl[(dt * 16 + col) * VROW + quad * 8];
      Oc[dt] = __builtin_amdgcn_mfma_f32_16x16x32_bf16(pa, vb, Oc[dt], 0, 0, 0);
    }
    __builtin_amdgcn_s_setprio(0);
  }

  // ---- merge the two in-block KV-group partials (exact online-softmax) ----
  // exchange region (36.9 KB) fits in LDS only 2 waves at a time: 2 rounds
  float* ex = (float*)sm;
#pragma unroll
  for (int rr = 0; rr < 2; rr++) {
    __syncthreads();
    if (g == 1 && (w >> 1) == rr) {
      float* slot = ex + (size_t)((w & 1) * 64 + lane) * XSTRIDE;
#pragma unroll
      for (int rg = 0; rg < 4; rg++) { slot[rg] = m_i[rg]; slot[4 + rg] = l_i[rg]; }
#pragma unroll
      for (int dt = 0; dt < 16; dt++) *(f32x4*)&slot[8 + dt * 4] = Oc[dt];
    }
    __syncthreads();
    if (g == 0 && (w >> 1) == rr) {
      const float* slot = ex + (size_t)((w & 1) * 64 + lane) * XSTRIDE;
      float a0[4], a1[4];
#pragma unroll
      for (int rg = 0; rg < 4; rg++) {
        const float m1 = slot[rg];
        const float l1 = slot[4 + rg];
        const float mm = fmaxf(m_i[rg], m1);
        a0[rg] = __expf(m_i[rg] - mm);
        a1[rg] = __expf(m1 - mm);
        m_i[rg] = mm;
        l_i[rg] = l_i[rg] * a0[rg] + l1 * a1[rg];
      }
#pragma unroll
      for (int dt = 0; dt < 16; dt++) {
        const f32x4 o1 = *(const f32x4*)&slot[8 + dt * 4];
#pragma unroll
        for (int rg = 0; rg < 4; rg++)
          Oc[dt][rg] = Oc[dt][rg] * a0[rg] + o1[rg] * a1[rg];
      }
    }
  }
  if (g == 0) {
    // unnormalized partial O for this KV half; z=0 -> out (scratch), z=1 -> O1
    float* op = (z ? O1 : out) + ((size_t)b * SS + qrow + quad * 4) * DD;
#pragma unroll
    for (int dt = 0; dt < 16; dt++) {
#pragma unroll
      for (int rg = 0; rg < 4; rg++)
        op[rg * DD + dt * 16 + col] = Oc[dt][rg];
    }
    if (col == 0) {
      float2* pml = (float2*)Ml + (size_t)z * BB * SS + (size_t)b * SS + qrow + quad * 4;
#pragma unroll
      for (int rg = 0; rg < 4; rg++) pml[rg] = make_float2(m_i[rg], l_i[rg]);
    }
  }
}

// ---------------- kernel 4: cross-z softmax merge ----------------
// out = (O0*a0 + O1*a1) / (l0*a0 + l1*a1), a_z = exp(m_z - max(m0,m1)).
__global__ __launch_bounds__(256) void merge_kernel(const float* __restrict__ Ml,
                                                    const float* __restrict__ O1,
                                                    float* __restrict__ out) {
  const int row = blockIdx.x * 4 + (threadIdx.x >> 6);  // 0..BB*SS-1
  const int lane = threadIdx.x & 63;
  const float2 ml0 = ((const float2*)Ml)[row];
  const float2 ml1 = ((const float2*)Ml)[BB * SS + row];
  const float mm = fmaxf(ml0.x, ml1.x);
  const float a0 = __expf(ml0.x - mm);
  const float a1 = __expf(ml1.x - mm);
  const float inv = 1.0f / (ml0.y * a0 + ml1.y * a1);
  f32x4* po = (f32x4*)out + (size_t)row * 64 + lane;
  const f32x4 o0 = *po;
  const f32x4 o1 = ((const f32x4*)O1)[(size_t)row * 64 + lane];
  f32x4 r;
#pragma unroll
  for (int j = 0; j < 4; j++) r[j] = (o0[j] * a0 + o1[j] * a1) * inv;
  *po = r;
}

extern "C" void kernel_launch(void* const* d_in, const int* in_sizes, int n_in,
                              void* d_out, int out_size, void* d_ws, size_t ws_size,
                              hipStream_t stream) {
  const float* X  = (const float*)d_in[0];
  const int* mask = (const int*)d_in[1];
  const float* Wq = (const float*)d_in[2];
  const float* bq = (const float*)d_in[3];
  const float* Wk = (const float*)d_in[4];
  const float* bk = (const float*)d_in[5];
  const float* Wv = (const float*)d_in[6];
  const float* bv = (const float*)d_in[7];
  float* out = (float*)d_out;

  ushort* base = (ushort*)d_ws;
  ushort* Xb = base;                                   // 8,388,608 B (dead after proj_gemm)
  ushort* Wb = Xb + (size_t)BB * SS * DD;              //   196,608 u
  ushort* Qb = Wb + (size_t)3 * DD * DD;
  ushort* Kb = Qb + (size_t)BB * SS * DD;
  ushort* Vt = Kb + (size_t)BB * SS * DD;
  float* bias = (float*)(Vt + (size_t)BB * SS * DD);   // 768 f32
  float* O1 = bias + 768;                              // 4,194,304 f32 (16.8 MB)
  float* Ml = O1 + (size_t)BB * SS * DD;               // 2*BB*SS float2 (0.26 MB)
  unsigned long long* Pm = (unsigned long long*)Xb;    // ALIASES Xb: 8,388,608 B exact
  // total ws ~= 51 MB (same layout/size as the passing R8 run)

  convert_kernel<<<1024, 256, 0, stream>>>(X, Wq, Wk, Wv, bq, bk, bv, Xb, Wb, bias);
  proj_gemm<<<dim3(128, 6), 256, 0, stream>>>(Xb, Wb, bias, Qb, Kb, Vt);
  maskpack_kernel<<<1024, 256, 0, stream>>>(mask, Pm);
  attn_kernel<<<dim3(64, 4, 2), 512, 0, stream>>>(Qb, Kb, Vt, (const uint*)Pm,
                                                  out, O1, Ml);
  merge_kernel<<<(BB * SS) / 4, 256, 0, stream>>>(Ml, O1, out);
}

// Round 12
// 521.009 us; speedup vs baseline: 1.3045x; 1.3045x over previous
//
#include <hip/hip_runtime.h>
#include <hip/hip_bf16.h>
#include <stdint.h>

#define BB 4
#define SS 4096
#define DD 256

typedef __attribute__((ext_vector_type(4))) float f32x4;
typedef __attribute__((ext_vector_type(8))) short s16x8;

__device__ __forceinline__ ushort f2bf(float f) {
  __hip_bfloat16 h = __float2bfloat16(f);
  return __builtin_bit_cast(ushort, h);
}

// pack 8 consecutive f32 -> 8 bf16 (RNE, identical to the old convert_kernel)
__device__ __forceinline__ s16x8 pack8(const float* __restrict__ p) {
  const float4 a = *(const float4*)p;
  const float4 b = *(const float4*)(p + 4);
  s16x8 r;
  r[0] = (short)f2bf(a.x); r[1] = (short)f2bf(a.y);
  r[2] = (short)f2bf(a.z); r[3] = (short)f2bf(a.w);
  r[4] = (short)f2bf(b.x); r[5] = (short)f2bf(b.y);
  r[6] = (short)f2bf(b.z); r[7] = (short)f2bf(b.w);
  return r;
}

// ---------------- kernel 1: fused convert + QKV projection GEMM ----------------
// R11 ledger: total - attn has been ~283-297 us in EVERY passing round while
// convert+proj+merge roofline is ~40-60 us -> suspected per-launch overhead.
// This round deletes the convert launch: stage X/W tiles directly from f32
// with inline bf16 conversion (same RNE numerics); bias read f32 in epilogue.
// (R11 also showed mask bit-packing is net-negative: attn -8 us, maskpack
// +174 us — attn is latency-bound, the 206 MB mask stream was only 12% of
// HBM BW and hides under stalls. Reverted to raw mask reads.)
#define LROW 40  // padded LDS row stride (bf16 elems); 80B: multiple of 16B (b128-safe)

__global__ __launch_bounds__(256) void proj_gemm(const float* __restrict__ X,
                                                 const float* __restrict__ Wq,
                                                 const float* __restrict__ Wk,
                                                 const float* __restrict__ Wv,
                                                 const float* __restrict__ bq,
                                                 const float* __restrict__ bk,
                                                 const float* __restrict__ bv,
                                                 ushort* __restrict__ Qb,
                                                 ushort* __restrict__ Kb,
                                                 ushort* __restrict__ Vt) {
  __shared__ ushort Al[128 * LROW];
  __shared__ ushort Bl[128 * LROW];
  const int m0 = blockIdx.x * 128;
  const int n0 = blockIdx.y * 128;
  const int region = n0 >> 8;          // 0=Q, 1=K, 2=V (blocks never straddle)
  const int n0l = n0 & 255;            // row offset within the region's W
  const float* Wsel = (region == 0) ? Wq : (region == 1) ? Wk : Wv;
  const float* bsel = (region == 0) ? bq : (region == 1) ? bk : bv;
  const int t = threadIdx.x;
  const int lane = t & 63;
  const int w = t >> 6;
  const int wr = w & 1, wc = w >> 1;
  const int col = lane & 15;
  const int quad = lane >> 4;

  f32x4 acc[4][4];
#pragma unroll
  for (int i = 0; i < 4; i++)
#pragma unroll
    for (int j = 0; j < 4; j++) acc[i][j] = f32x4{0.f, 0.f, 0.f, 0.f};

  const int ci0 = t, ci1 = 256 + t;
  const int r0 = ci0 >> 2, c0 = ci0 & 3;
  const int r1 = ci1 >> 2, c1 = ci1 & 3;

  // prefetch K-step 0 (f32 -> bf16 in regs)
  s16x8 pa0 = pack8(X + (size_t)(m0 + r0) * DD + c0 * 8);
  s16x8 pa1 = pack8(X + (size_t)(m0 + r1) * DD + c1 * 8);
  s16x8 pb0 = pack8(Wsel + (size_t)(n0l + r0) * DD + c0 * 8);
  s16x8 pb1 = pack8(Wsel + (size_t)(n0l + r1) * DD + c1 * 8);

  for (int kk = 0; kk < DD; kk += 32) {
    __syncthreads();
    *(s16x8*)&Al[r0 * LROW + c0 * 8] = pa0;
    *(s16x8*)&Al[r1 * LROW + c1 * 8] = pa1;
    *(s16x8*)&Bl[r0 * LROW + c0 * 8] = pb0;
    *(s16x8*)&Bl[r1 * LROW + c1 * 8] = pb1;
    __syncthreads();
    const int kn = kk + 32;
    if (kn < DD) {
      pa0 = pack8(X + (size_t)(m0 + r0) * DD + kn + c0 * 8);
      pa1 = pack8(X + (size_t)(m0 + r1) * DD + kn + c1 * 8);
      pb0 = pack8(Wsel + (size_t)(n0l + r0) * DD + kn + c0 * 8);
      pb1 = pack8(Wsel + (size_t)(n0l + r1) * DD + kn + c1 * 8);
    }
    s16x8 af[4], bfr[4];
#pragma unroll
    for (int mi = 0; mi < 4; mi++)
      af[mi] = *(const s16x8*)&Al[(wr * 64 + mi * 16 + col) * LROW + quad * 8];
#pragma unroll
    for (int ni = 0; ni < 4; ni++)
      bfr[ni] = *(const s16x8*)&Bl[(wc * 64 + ni * 16 + col) * LROW + quad * 8];
#pragma unroll
    for (int mi = 0; mi < 4; mi++)
#pragma unroll
      for (int ni = 0; ni < 4; ni++)
        acc[mi][ni] = __builtin_amdgcn_mfma_f32_16x16x32_bf16(af[mi], bfr[ni], acc[mi][ni], 0, 0, 0);
  }

#pragma unroll
  for (int mi = 0; mi < 4; mi++) {
    const int gm = m0 + wr * 64 + mi * 16 + quad * 4;
#pragma unroll
    for (int ni = 0; ni < 4; ni++) {
      const int gnl = n0l + wc * 64 + ni * 16 + col;  // 0..255 within region
      const float bb = bsel[gnl];
      f32x4 v = acc[mi][ni];
      if (region == 0) {
#pragma unroll
        for (int rg = 0; rg < 4; rg++)
          Qb[(size_t)(gm + rg) * DD + gnl] = f2bf((v[rg] + bb) * 0.015625f);  // exact /64
      } else if (region == 1) {
#pragma unroll
        for (int rg = 0; rg < 4; rg++)
          Kb[(size_t)(gm + rg) * DD + gnl] = f2bf(v[rg] + bb);
      } else {
        const int b = gm >> 12;
        const int s = gm & (SS - 1);
        ushort4 o = { f2bf(v[0] + bb), f2bf(v[1] + bb), f2bf(v[2] + bb), f2bf(v[3] + bb) };
        *(ushort4*)&Vt[((size_t)(b << 8) + gnl) * SS + s] = o;  // C-regs run along m=s
      }
    }
  }
}

// ---------------- kernel 2: flash attention ----------------
// Grid (64 qt, 4 b, 2 z): 512 blocks x 512 threads. Block z handles KV rows
// [z*2048, z*2048+2048) over 2 in-block KV groups; partials merged in LDS,
// then cross-z by merge_kernel. K/V time-share one LDS region (R8).
// OCCUPANCY NOTE (R7/R8): stuck at 8 waves/CU with LDS 42-75 KB and grid
// 2 blocks/CU — blocker is register file (104 arch VGPR + 64 MFMA AGPRs >
// 128 total/wave at 4 waves/SIMD), not LDS.
// ALIGNMENT RULE (R6): LDS row strides must be multiples of 8 ushorts (16 B)
// or ds_*_b128 splits into b64 pairs (3x per-tile cost).
#define NKT 32
#define KROW 264   // 528B, 16B-aligned
#define VROW 32    //  64B, 16B-aligned
#define PROW 32

#define KVREG_U 8448             // max(K tile 32*264=8448, V tile 256*32=8192)
#define PL_U (16 * PROW)         // 512 per wave
#define POFF (2 * KVREG_U)       // 16896
#define SM_U (POFF + 8 * PL_U)   // 20992 ushorts = 41984 B

// exchange slot: 72 f32 (m[4], l[4], O[64]); 2 waves/round: 128*72*4 = 36864 B
#define XSTRIDE 72

__global__ __launch_bounds__(512) void attn_kernel(const ushort* __restrict__ Qb,
                                                   const ushort* __restrict__ Kb,
                                                   const ushort* __restrict__ Vt,
                                                   const int* __restrict__ mask,
                                                   float* __restrict__ out,
                                                   float* __restrict__ O1,
                                                   float* __restrict__ Ml) {
  __shared__ __align__(16) ushort sm[SM_U];

  const int qt = blockIdx.x;  // 0..63
  const int b = blockIdx.y;   // 0..3
  const int z = blockIdx.z;   // 0..1 (KV half)
  const int t = threadIdx.x;
  const int g = t >> 8;       // in-block KV group: 0 or 1
  const int tg = t & 255;     // thread within group
  const int lane = t & 63;
  const int w = tg >> 6;      // row-wave within group: 0..3
  const int w8 = t >> 6;      // global wave: 0..7
  const int col = lane & 15;
  const int quad = lane >> 4;

  ushort* Kl = sm + g * KVREG_U;   // K and V time-share this region
  ushort* Vl = sm + g * KVREG_U;
  ushort* Pw = sm + POFF + w8 * PL_U;

  const int q0 = qt * 64;
  const int qrow = q0 + w * 16;  // wave's first q row (within batch)

  // Q fragments (A-operand), pre-scaled by 1/64
  s16x8 qf[8];
  {
    const ushort* qp = Qb + ((size_t)b * SS + qrow + col) * DD + quad * 8;
#pragma unroll
    for (int dc = 0; dc < 8; dc++) qf[dc] = *(const s16x8*)(qp + dc * 32);
  }

  int kr[4], kc[4], vd[4], vc[4];
#pragma unroll
  for (int i = 0; i < 4; i++) {
    const int ci = i * 256 + tg;
    kr[i] = ci >> 5; kc[i] = ci & 31;  // K tile: 32 rows x 32 chunks(8)
    vd[i] = ci >> 2; vc[i] = ci & 3;   // Vt tile: 256 d-rows x 4 chunks(8)
  }

  const ushort* Kg = Kb + (size_t)b * SS * DD;
  const ushort* Vg = Vt + (size_t)b * DD * SS;
  const int* Mg = mask + ((size_t)b * SS + qrow + quad * 4) * SS;

  f32x4 Oc[16];
#pragma unroll
  for (int i = 0; i < 16; i++) Oc[i] = f32x4{0.f, 0.f, 0.f, 0.f};
  float m_i[4] = {-INFINITY, -INFINITY, -INFINITY, -INFINITY};
  float l_i[4] = {0.f, 0.f, 0.f, 0.f};

  const int NT2 = 1024 / NKT;             // 32 tiles per in-block group
  const int kb0 = z * 2048 + g * 1024;    // group's first kv position

  // prefetch this group's tile 0 into registers
  s16x8 pk[4], pv[4];
  int pm[2][4];
#pragma unroll
  for (int i = 0; i < 4; i++) {
    pk[i] = *(const s16x8*)(Kg + (size_t)(kb0 + kr[i]) * DD + kc[i] * 8);
    pv[i] = *(const s16x8*)(Vg + (size_t)vd[i] * SS + kb0 + vc[i] * 8);
  }
#pragma unroll
  for (int jt = 0; jt < 2; jt++)
#pragma unroll
    for (int rg = 0; rg < 4; rg++) pm[jt][rg] = Mg[rg * SS + kb0 + jt * 16 + col];

  for (int tt = 0; tt < NT2; tt++) {
    __syncthreads();   // B1: prior PV reads of shared region done
#pragma unroll
    for (int i = 0; i < 4; i++)
      *(s16x8*)&Kl[kr[i] * KROW + kc[i] * 8] = pk[i];
    __syncthreads();   // B2: K tile visible
    int mcur[2][4];
#pragma unroll
    for (int jt = 0; jt < 2; jt++)
#pragma unroll
      for (int rg = 0; rg < 4; rg++) mcur[jt][rg] = pm[jt][rg];
    const int k0n = kb0 + (tt + 1) * NKT;
    if (tt + 1 < NT2) {
#pragma unroll
      for (int i = 0; i < 4; i++)
        pk[i] = *(const s16x8*)(Kg + ((size_t)k0n + kr[i]) * DD + kc[i] * 8);
#pragma unroll
      for (int jt = 0; jt < 2; jt++)
#pragma unroll
        for (int rg = 0; rg < 4; rg++) pm[jt][rg] = Mg[rg * SS + k0n + jt * 16 + col];
    }

    // S = Q K^T (pre-scaled): 2 col-tiles x 8 d-chunks
    f32x4 st[2];
    __builtin_amdgcn_s_setprio(1);
#pragma unroll
    for (int jt = 0; jt < 2; jt++) {
      f32x4 s = f32x4{0.f, 0.f, 0.f, 0.f};
#pragma unroll
      for (int dc = 0; dc < 8; dc++) {
        s16x8 kb = *(const s16x8*)&Kl[(jt * 16 + col) * KROW + dc * 32 + quad * 8];
        s = __builtin_amdgcn_mfma_f32_16x16x32_bf16(qf[dc], kb, s, 0, 0, 0);
      }
      st[jt] = s;
    }
    __builtin_amdgcn_s_setprio(0);
    // mask (nonzero -> -1e9, post-scale, matching reference)
#pragma unroll
    for (int jt = 0; jt < 2; jt++)
#pragma unroll
      for (int rg = 0; rg < 4; rg++)
        if (mcur[jt][rg]) st[jt][rg] = -1e9f;

    // online softmax: per q-row (row = quad*4+rg), reduce over 16 col lanes
    float al[4];
#pragma unroll
    for (int rg = 0; rg < 4; rg++) {
      float v = fmaxf(st[0][rg], st[1][rg]);
      v = fmaxf(v, __shfl_xor(v, 1));
      v = fmaxf(v, __shfl_xor(v, 2));
      v = fmaxf(v, __shfl_xor(v, 4));
      v = fmaxf(v, __shfl_xor(v, 8));
      const float mn = fmaxf(m_i[rg], v);
      al[rg] = __expf(m_i[rg] - mn);
      m_i[rg] = mn;
    }
#pragma unroll
    for (int rg = 0; rg < 4; rg++) {
      const float p0 = __expf(st[0][rg] - m_i[rg]);
      const float p1 = __expf(st[1][rg] - m_i[rg]);
      st[0][rg] = p0; st[1][rg] = p1;
      float s2 = p0 + p1;
      s2 += __shfl_xor(s2, 1);
      s2 += __shfl_xor(s2, 2);
      s2 += __shfl_xor(s2, 4);
      s2 += __shfl_xor(s2, 8);
      l_i[rg] = l_i[rg] * al[rg] + s2;
    }

    // P: C-layout -> LDS -> A-layout (own region, same-wave dependency only)
#pragma unroll
    for (int jt = 0; jt < 2; jt++)
#pragma unroll
      for (int rg = 0; rg < 4; rg++)
        Pw[(quad * 4 + rg) * PROW + jt * 16 + col] = f2bf(st[jt][rg]);
    s16x8 pa = *(const s16x8*)&Pw[col * PROW + quad * 8];

    // O rescale — EXACT skip: al==1.0 means multiply-by-1, identity.
    {
      const bool need = (al[0] < 1.f) | (al[1] < 1.f) | (al[2] < 1.f) | (al[3] < 1.f);
      if (__any(need)) {
#pragma unroll
        for (int dt = 0; dt < 16; dt++)
#pragma unroll
          for (int rg = 0; rg < 4; rg++) Oc[dt][rg] *= al[rg];
      }
    }

    __syncthreads();   // B3: all QK^T reads done; shared region free for V
#pragma unroll
    for (int i = 0; i < 4; i++)
      *(s16x8*)&Vl[vd[i] * VROW + vc[i] * 8] = pv[i];
    if (tt + 1 < NT2) {  // prefetch next V only after current V consumed
#pragma unroll
      for (int i = 0; i < 4; i++)
        pv[i] = *(const s16x8*)(Vg + (size_t)vd[i] * SS + k0n + vc[i] * 8);
    }
    __syncthreads();   // B4: V tile visible

    // O += P * V
    __builtin_amdgcn_s_setprio(1);
#pragma unroll
    for (int dt = 0; dt < 16; dt++) {
      s16x8 vb = *(const s16x8*)&Vl[(dt * 16 + col) * VROW + quad * 8];
      Oc[dt] = __builtin_amdgcn_mfma_f32_16x16x32_bf16(pa, vb, Oc[dt], 0, 0, 0);
    }
    __builtin_amdgcn_s_setprio(0);
  }

  // ---- merge the two in-block KV-group partials (exact online-softmax) ----
  // exchange region (36.9 KB) fits in LDS only 2 waves at a time: 2 rounds
  float* ex = (float*)sm;
#pragma unroll
  for (int rr = 0; rr < 2; rr++) {
    __syncthreads();
    if (g == 1 && (w >> 1) == rr) {
      float* slot = ex + (size_t)((w & 1) * 64 + lane) * XSTRIDE;
#pragma unroll
      for (int rg = 0; rg < 4; rg++) { slot[rg] = m_i[rg]; slot[4 + rg] = l_i[rg]; }
#pragma unroll
      for (int dt = 0; dt < 16; dt++) *(f32x4*)&slot[8 + dt * 4] = Oc[dt];
    }
    __syncthreads();
    if (g == 0 && (w >> 1) == rr) {
      const float* slot = ex + (size_t)((w & 1) * 64 + lane) * XSTRIDE;
      float a0[4], a1[4];
#pragma unroll
      for (int rg = 0; rg < 4; rg++) {
        const float m1 = slot[rg];
        const float l1 = slot[4 + rg];
        const float mm = fmaxf(m_i[rg], m1);
        a0[rg] = __expf(m_i[rg] - mm);
        a1[rg] = __expf(m1 - mm);
        m_i[rg] = mm;
        l_i[rg] = l_i[rg] * a0[rg] + l1 * a1[rg];
      }
#pragma unroll
      for (int dt = 0; dt < 16; dt++) {
        const f32x4 o1 = *(const f32x4*)&slot[8 + dt * 4];
#pragma unroll
        for (int rg = 0; rg < 4; rg++)
          Oc[dt][rg] = Oc[dt][rg] * a0[rg] + o1[rg] * a1[rg];
      }
    }
  }
  if (g == 0) {
    // unnormalized partial O for this KV half; z=0 -> out (scratch), z=1 -> O1
    float* op = (z ? O1 : out) + ((size_t)b * SS + qrow + quad * 4) * DD;
#pragma unroll
    for (int dt = 0; dt < 16; dt++) {
#pragma unroll
      for (int rg = 0; rg < 4; rg++)
        op[rg * DD + dt * 16 + col] = Oc[dt][rg];
    }
    if (col == 0) {
      float2* pml = (float2*)Ml + (size_t)z * BB * SS + (size_t)b * SS + qrow + quad * 4;
#pragma unroll
      for (int rg = 0; rg < 4; rg++) pml[rg] = make_float2(m_i[rg], l_i[rg]);
    }
  }
}

// ---------------- kernel 3: cross-z softmax merge ----------------
// out = (O0*a0 + O1*a1) / (l0*a0 + l1*a1), a_z = exp(m_z - max(m0,m1)).
__global__ __launch_bounds__(256) void merge_kernel(const float* __restrict__ Ml,
                                                    const float* __restrict__ O1,
                                                    float* __restrict__ out) {
  const int row = blockIdx.x * 4 + (threadIdx.x >> 6);  // 0..BB*SS-1
  const int lane = threadIdx.x & 63;
  const float2 ml0 = ((const float2*)Ml)[row];
  const float2 ml1 = ((const float2*)Ml)[BB * SS + row];
  const float mm = fmaxf(ml0.x, ml1.x);
  const float a0 = __expf(ml0.x - mm);
  const float a1 = __expf(ml1.x - mm);
  const float inv = 1.0f / (ml0.y * a0 + ml1.y * a1);
  f32x4* po = (f32x4*)out + (size_t)row * 64 + lane;
  const f32x4 o0 = *po;
  const f32x4 o1 = ((const f32x4*)O1)[(size_t)row * 64 + lane];
  f32x4 r;
#pragma unroll
  for (int j = 0; j < 4; j++) r[j] = (o0[j] * a0 + o1[j] * a1) * inv;
  *po = r;
}

extern "C" void kernel_launch(void* const* d_in, const int* in_sizes, int n_in,
                              void* d_out, int out_size, void* d_ws, size_t ws_size,
                              hipStream_t stream) {
  const float* X  = (const float*)d_in[0];
  const int* mask = (const int*)d_in[1];
  const float* Wq = (const float*)d_in[2];
  const float* bq = (const float*)d_in[3];
  const float* Wk = (const float*)d_in[4];
  const float* bk = (const float*)d_in[5];
  const float* Wv = (const float*)d_in[6];
  const float* bv = (const float*)d_in[7];
  float* out = (float*)d_out;

  ushort* base = (ushort*)d_ws;
  ushort* Qb = base;                                   // 4,194,304 u (8.4 MB)
  ushort* Kb = Qb + (size_t)BB * SS * DD;              // 8.4 MB
  ushort* Vt = Kb + (size_t)BB * SS * DD;              // 8.4 MB
  float* O1 = (float*)(Vt + (size_t)BB * SS * DD);     // 16.8 MB
  float* Ml = O1 + (size_t)BB * SS * DD;               // 2*BB*SS float2 (0.26 MB)
  // total ws ~= 42.3 MB (below the 51 MB proven-good bound)

  proj_gemm<<<dim3(128, 6), 256, 0, stream>>>(X, Wq, Wk, Wv, bq, bk, bv, Qb, Kb, Vt);
  attn_kernel<<<dim3(64, 4, 2), 512, 0, stream>>>(Qb, Kb, Vt, mask, out, O1, Ml);
  merge_kernel<<<(BB * SS) / 4, 256, 0, stream>>>(Ml, O1, out);
}